// Round 1
// 964.943 us; speedup vs baseline: 1.0892x; 1.0892x over previous
//
#include <hip/hip_runtime.h>
#include <hip/hip_bf16.h>
#include <stdint.h>

// LinearPatchMerger: (1,131072,1024) fp32 patches, merge 2x2 -> (32768,4096),
// out = merged @ W.T, W (1024,4096) fp32. Output (1,32768,1024) fp32.
//
// Round-3 strategy (fast path, needs ws >= 264 MiB):
//   pass 1: repack W -> bf16, K-permuted (k' = s*1024 + d)          [8 MiB]
//   pass 2: gather+convert X -> merged bf16 A' (32768 x 4096)       [256 MiB]
//   pass 3: 256x256x64 8-phase bf16 GEMM (HK-style schedule):
//           8 waves (2Mx4N), 128 KiB LDS double-buffer in quadrant-
//           grouped 16 KiB halves, st_16x32 XOR swizzle (pre-swizzled
//           global_load_lds source), counted s_waitcnt vmcnt(6) at
//           phases 3/7, s_setprio(1) around MFMA clusters, XCD-chunked
//           block swizzle (512 blocks, 64/XCD).
// Fallback (small ws): round-1 fused gather-GEMM (passed, ~600 us).

#define M_TOTAL 32768
#define K_DIM   4096
#define N_DIM   1024
#define BM 128
#define BN 128
#define BK 64

typedef __attribute__((ext_vector_type(8))) short short8;
typedef __attribute__((ext_vector_type(4))) float f32x4;
typedef __attribute__((ext_vector_type(8))) unsigned short us8;

#define ASYNC_COPY16(gsrc, ldst)                                                     \
    __builtin_amdgcn_global_load_lds(                                                \
        (const __attribute__((address_space(1))) unsigned int*)(const void*)(gsrc),  \
        (__attribute__((address_space(3))) unsigned int*)(ldst), 16, 0, 0)

static __device__ __forceinline__ unsigned pack2bf(float lo, float hi) {
    unsigned a = __builtin_bit_cast(unsigned, lo) + 0x8000u;
    unsigned b = __builtin_bit_cast(unsigned, hi) + 0x8000u;
    return __builtin_amdgcn_perm(b, a, 0x07060302);
}

// ---------------- pass 1: Wp[j, s*1024+d] = bf16(W[j, d*4+s]) ----------------
__global__ __launch_bounds__(256) void repack_w(const float* __restrict__ W,
                                                unsigned short* __restrict__ Wp) {
    int t = blockIdx.x * 256 + threadIdx.x;
    int j  = t >> 8;
    int d0 = (t & 255) << 2;
    const float4* src = (const float4*)(W + (size_t)j * K_DIM + (size_t)d0 * 4);
    float4 v0 = src[0], v1 = src[1], v2 = src[2], v3 = src[3];
    float vs[4][4] = {{v0.x, v1.x, v2.x, v3.x},
                      {v0.y, v1.y, v2.y, v3.y},
                      {v0.z, v1.z, v2.z, v3.z},
                      {v0.w, v1.w, v2.w, v3.w}};
#pragma unroll
    for (int s = 0; s < 4; s++) {
        uint2 o;
        o.x = pack2bf(vs[s][0], vs[s][1]);
        o.y = pack2bf(vs[s][2], vs[s][3]);
        *(uint2*)(Wp + (size_t)j * K_DIM + s * 1024 + d0) = o;
    }
}

// -------- pass 2: A'[m, s*1024+d] = bf16(X[p, d]); 16 floats/thread ---------
__global__ __launch_bounds__(256) void gather_convert(const float* __restrict__ X,
                                                      unsigned short* __restrict__ Ap) {
    int idx = blockIdx.x * 256 + threadIdx.x;   // 8.39M threads
    int p   = idx >> 6;                          // 64 threads per patch row
    int c16 = (idx & 63) << 4;                   // float col, 16 per thread
    int img = p >> 14;
    int r   = p & 16383;
    int pi  = r >> 7;
    int pj  = r & 127;
    int m   = img * 4096 + (pi >> 1) * 64 + (pj >> 1);
    int s   = ((pi & 1) << 1) | (pj & 1);
    const float4* src = (const float4*)(X + (size_t)p * 1024 + c16);
    float4 v0 = src[0], v1 = src[1], v2 = src[2], v3 = src[3];
    uint4 o0, o1;
    o0.x = pack2bf(v0.x, v0.y); o0.y = pack2bf(v0.z, v0.w);
    o0.z = pack2bf(v1.x, v1.y); o0.w = pack2bf(v1.z, v1.w);
    o1.x = pack2bf(v2.x, v2.y); o1.y = pack2bf(v2.z, v2.w);
    o1.z = pack2bf(v3.x, v3.y); o1.w = pack2bf(v3.z, v3.w);
    uint4* dst = (uint4*)(Ap + (size_t)m * K_DIM + s * 1024 + c16);
    dst[0] = o0;
    dst[1] = o1;
}

// ---------------- pass 3: 256x256x64 8-phase bf16 GEMM ----------------------
// LDS: lds[slot][op][half] of 16 KiB halves. Half = 8 slabs x 2 subtiles of
// [16 rows][32 cols] bf16 (1024 B), st_16x32 XOR: byte ^= ((byte>>9)&1)<<5.
// A-half h holds tile rows {wr*128 + h*64 + [0,64)}; B-half h holds rows
// {wc*64 + h*32 + [0,32)} (quadrant-grouped so each half dies one phase
// before the stage that overwrites it).
// Schedule per iter t (K-tiles 2t->slot0 phases 0-3, 2t+1->slot1 phases 4-7):
//   ph0: stage slot1<-odd:A-h1 | ph1-4: stage slot0<-next-even B0,A0,B1,A1
//   ph5-7: stage slot1<-next-odd B0,A0,B1   (next-odd A-h1 at next ph0)
//   vmcnt(6)+barrier at ph3/ph7 => stages through ph0/ph4 landed (per-wave
//   vmcnt + barrier jointly gives the block-wide guarantee).
#define NT 32   // 64 K-tiles / 2 per iteration

#define SBAR() do { asm volatile("" ::: "memory");            \
                    __builtin_amdgcn_s_barrier();             \
                    asm volatile("" ::: "memory"); } while (0)
#define WAITLG()  asm volatile("s_waitcnt lgkmcnt(0)" ::: "memory")
#define WAITVM6() asm volatile("s_waitcnt vmcnt(6)" ::: "memory")

__global__ __launch_bounds__(512, 2) void gemm_8p(
        const unsigned short* __restrict__ Ap,  // (32768,4096) bf16, permuted K
        const unsigned short* __restrict__ Wp,  // (1024,4096) bf16, permuted K
        float* __restrict__ out) {              // (32768,1024) fp32
    __shared__ unsigned short lds[2][2][2][8192];  // 128 KiB

    const int tid  = threadIdx.x;
    const int lane = tid & 63;
    const int wave = tid >> 6;      // 8 waves: wr = wave>>2 (M), wc = wave&3 (N)
    const int wr   = wave >> 2;
    const int wc   = wave & 3;
    const int lrow = lane & 15;
    const int quad = lane >> 4;

    // XCD-chunked bijective swizzle: 512 blocks, 64 per XCD; n-minor so the
    // 4 blocks sharing an A panel are adjacent within one XCD's chunk.
    const int bid = blockIdx.x;
    const int lw  = (bid & 7) * 64 + (bid >> 3);
    const int bn  = (lw & 3) * 256;
    const int bm  = (lw >> 2) * 256;

    // Staging source addressing. global_load_lds writes lane l at subtile
    // byte l*16; with the XOR involution that physical slot holds logical
    // (row = l>>2, chunk = (l&3)^((l>>5)<<1)) -> pre-swizzle the source.
    const int rho   = lane >> 2;
    const int kappa = (lane & 3) ^ ((lane >> 5) << 1);
    const int r128s = wave * 16 + rho;          // wave stages slab==wave
    const unsigned short* aptr[2];
    const unsigned short* bptr[2];
#pragma unroll
    for (int h = 0; h < 2; h++) {
        const int ra = ((r128s >> 6) << 7) + h * 64 + (r128s & 63);
        const int rb = ((r128s >> 5) << 6) + h * 32 + (r128s & 31);
        aptr[h] = Ap + (size_t)(bm + ra) * K_DIM + kappa * 8;
        bptr[h] = Wp + (size_t)(bn + rb) * K_DIM + kappa * 8;
    }

#define STAGE_A(slot, h, kt) do {                                                 \
    ASYNC_COPY16(aptr[h] + (kt) * 64,      &lds[slot][0][h][wave * 1024]);        \
    ASYNC_COPY16(aptr[h] + (kt) * 64 + 32, &lds[slot][0][h][wave * 1024 + 512]);  \
} while (0)
#define STAGE_B(slot, h, kt) do {                                                 \
    ASYNC_COPY16(bptr[h] + (kt) * 64,      &lds[slot][1][h][wave * 1024]);        \
    ASYNC_COPY16(bptr[h] + (kt) * 64 + 32, &lds[slot][1][h][wave * 1024 + 512]);  \
} while (0)

    // ds_read swizzled row/chunk offset within a subtile (16-B aligned)
    const int rswz = (lrow * 64 + quad * 16) ^ ((lrow & 8) << 2);
    short8 a[4][2], b0[2][2], b1[2][2];
    f32x4 acc[8][4] = {};

#define LDA(slot, mh) do {                                                        \
    const char* base_ = (const char*)&lds[slot][0][mh][0] + rswz;                 \
    _Pragma("unroll") for (int ii = 0; ii < 4; ii++)                              \
    _Pragma("unroll") for (int kk = 0; kk < 2; kk++)                              \
        a[ii][kk] = *(const short8*)(base_ + (wr * 4 + ii) * 2048 + kk * 1024);   \
} while (0)
#define LDB(slot, nh, breg) do {                                                  \
    const char* base_ = (const char*)&lds[slot][1][nh][0] + rswz;                 \
    _Pragma("unroll") for (int jj = 0; jj < 2; jj++)                              \
    _Pragma("unroll") for (int kk = 0; kk < 2; kk++)                              \
        breg[jj][kk] = *(const short8*)(base_ + (wc * 2 + jj) * 2048 + kk * 1024);\
} while (0)
#define MMA(mh, nh, breg) do {                                                    \
    _Pragma("unroll") for (int ii = 0; ii < 4; ii++)                              \
    _Pragma("unroll") for (int jj = 0; jj < 2; jj++)                              \
    _Pragma("unroll") for (int kk = 0; kk < 2; kk++)                              \
        acc[(mh) * 4 + ii][(nh) * 2 + jj] =                                       \
            __builtin_amdgcn_mfma_f32_16x16x32_bf16(                              \
                a[ii][kk], breg[jj][kk], acc[(mh) * 4 + ii][(nh) * 2 + jj],       \
                0, 0, 0);                                                         \
} while (0)

    // prologue: K-tile 0 (4 halves) -> slot0; K-tile 1 first 3 halves -> slot1
    STAGE_B(0, 0, 0); STAGE_A(0, 0, 0); STAGE_B(0, 1, 0); STAGE_A(0, 1, 0);
    STAGE_B(1, 0, 1); STAGE_A(1, 0, 1); STAGE_B(1, 1, 1);
    WAITVM6();        // all of K-tile 0 landed (3 half-tiles may stay in flight)
    SBAR();

#pragma unroll 1
    for (int t = 0; t < NT; t++) {
        const int ko = 2 * t + 1;          // this iteration's odd K-tile
        const int ne = (2 * t + 2) & 63;   // next even (wraps harmlessly at end)
        const int no = (2 * t + 3) & 63;   // next odd

        // phase 0: read e:A[mh0]+e:B[nh0]; stage odd A-h1; MFMA Q(0,0) even
        LDA(0, 0); LDB(0, 0, b0);
        STAGE_A(1, 1, ko);
        SBAR(); WAITLG();
        __builtin_amdgcn_s_setprio(1); MMA(0, 0, b0); __builtin_amdgcn_s_setprio(0);
        SBAR();
        // phase 1: read e:B[nh1]; stage ne B-h0; MFMA Q(0,1) even
        LDB(0, 1, b1);
        STAGE_B(0, 0, ne);
        SBAR(); WAITLG();
        __builtin_amdgcn_s_setprio(1); MMA(0, 1, b1); __builtin_amdgcn_s_setprio(0);
        SBAR();
        // phase 2: read e:A[mh1]; stage ne A-h0; MFMA Q(1,0) even
        LDA(0, 1);
        STAGE_A(0, 0, ne);
        SBAR(); WAITLG();
        __builtin_amdgcn_s_setprio(1); MMA(1, 0, b0); __builtin_amdgcn_s_setprio(0);
        SBAR();
        // phase 3: stage ne B-h1; MFMA Q(1,1) even; vmcnt(6) gates odd K-tile
        STAGE_B(0, 1, ne);
        SBAR();
        __builtin_amdgcn_s_setprio(1); MMA(1, 1, b1); __builtin_amdgcn_s_setprio(0);
        WAITVM6();
        SBAR();
        // phase 4: read o:A[mh0]+o:B[nh0]; stage ne A-h1; MFMA Q(0,0) odd
        LDA(1, 0); LDB(1, 0, b0);
        STAGE_A(0, 1, ne);
        SBAR(); WAITLG();
        __builtin_amdgcn_s_setprio(1); MMA(0, 0, b0); __builtin_amdgcn_s_setprio(0);
        SBAR();
        // phase 5: read o:B[nh1]; stage no B-h0; MFMA Q(0,1) odd
        LDB(1, 1, b1);
        STAGE_B(1, 0, no);
        SBAR(); WAITLG();
        __builtin_amdgcn_s_setprio(1); MMA(0, 1, b1); __builtin_amdgcn_s_setprio(0);
        SBAR();
        // phase 6: read o:A[mh1]; stage no A-h0; MFMA Q(1,0) odd
        LDA(1, 1);
        STAGE_A(1, 0, no);
        SBAR(); WAITLG();
        __builtin_amdgcn_s_setprio(1); MMA(1, 0, b0); __builtin_amdgcn_s_setprio(0);
        SBAR();
        // phase 7: stage no B-h1; MFMA Q(1,1) odd; vmcnt(6) gates next even
        STAGE_B(1, 1, no);
        SBAR();
        __builtin_amdgcn_s_setprio(1); MMA(1, 1, b1); __builtin_amdgcn_s_setprio(0);
        WAITVM6();
        SBAR();
    }

    asm volatile("s_waitcnt vmcnt(0)" ::: "memory");  // drain before endpgm

    const int ocol = bn + wc * 64 + lrow;
#pragma unroll
    for (int i = 0; i < 8; i++) {
#pragma unroll
        for (int r = 0; r < 4; r++) {
            float* po = out + (size_t)(bm + wr * 128 + i * 16 + quad * 4 + r) * N_DIM + ocol;
#pragma unroll
            for (int j = 0; j < 4; j++)
                po[j * 16] = acc[i][j][r];
        }
    }
}

// ---------------- fallback: round-1 fused gather-GEMM (passed) --------------
#define LP 72
__global__ __launch_bounds__(256) void merge_gemm(
        const float* __restrict__ X,
        const unsigned short* __restrict__ Wp,
        float* __restrict__ out) {
    __shared__ unsigned short As[BM][LP];
    __shared__ unsigned short Bs[BN][LP];

    const int tid  = threadIdx.x;
    const int lane = tid & 63;
    const int wave = tid >> 6;
    const int wm   = (wave >> 1) * 64;
    const int wn   = (wave & 1) * 64;
    const int lrow = lane & 15;
    const int quad = lane >> 4;

    const int blk = blockIdx.x;
    const int bn  = (blk & 7) * BN;
    const int bm  = (blk >> 3) * BM;

    const int arow = tid >> 4;
    const int acol = (tid & 15) << 2;

    const float* abase[8];
#pragma unroll
    for (int rep = 0; rep < 8; rep++) {
        int m   = bm + arow + rep * 16;
        int img = m >> 12;
        int r   = m & 4095;
        int bi  = r >> 6;
        int bj  = r & 63;
        int pbase = img * 16384 + bi * 256 + bj * 2;
        abase[rep] = X + (size_t)pbase * 1024 + acol;
    }

    const int brow = tid >> 3;
    const int bcol = (tid & 7) << 3;

    f32x4 acc[4][4] = {};

    for (int k0 = 0; k0 < K_DIM; k0 += BK) {
        const int s    = k0 >> 10;
        const int d0   = k0 & 1023;
        const int aoff = (((s >> 1) * 128) + (s & 1)) * 1024 + d0;

#pragma unroll
        for (int rep = 0; rep < 8; rep++) {
            const float4 v = *(const float4*)(abase[rep] + aoff);
            uint2 o;
            o.x = pack2bf(v.x, v.y);
            o.y = pack2bf(v.z, v.w);
            *(uint2*)&As[arow + rep * 16][acol] = o;
        }
#pragma unroll
        for (int rep = 0; rep < 4; rep++) {
            us8 v = *(const us8*)(Wp + (size_t)(bn + brow + rep * 32) * K_DIM + k0 + bcol);
            *(us8*)&Bs[brow + rep * 32][bcol] = v;
        }
        __syncthreads();

#pragma unroll
        for (int kk = 0; kk < 2; kk++) {
            const int koff = kk * 32 + quad * 8;
            short8 a[4], b[4];
#pragma unroll
            for (int i = 0; i < 4; i++)
                a[i] = *(const short8*)&As[wm + i * 16 + lrow][koff];
#pragma unroll
            for (int j = 0; j < 4; j++)
                b[j] = *(const short8*)&Bs[wn + j * 16 + lrow][koff];
#pragma unroll
            for (int i = 0; i < 4; i++)
#pragma unroll
                for (int j = 0; j < 4; j++)
                    acc[i][j] = __builtin_amdgcn_mfma_f32_16x16x32_bf16(
                        a[i], b[j], acc[i][j], 0, 0, 0);
        }
        __syncthreads();
    }

    const int ocol = bn + wn + lrow;
#pragma unroll
    for (int i = 0; i < 4; i++) {
#pragma unroll
        for (int r = 0; r < 4; r++) {
            float* po = out + (size_t)(bm + wm + i * 16 + quad * 4 + r) * N_DIM + ocol;
#pragma unroll
            for (int j = 0; j < 4; j++)
                po[j * 16] = acc[i][j][r];
        }
    }
}

extern "C" void kernel_launch(void* const* d_in, const int* in_sizes, int n_in,
                              void* d_out, int out_size, void* d_ws, size_t ws_size,
                              hipStream_t stream) {
    const float* X = (const float*)d_in[0];
    const float* W = (const float*)d_in[2];
    float* out = (float*)d_out;

    unsigned short* Wp = (unsigned short*)d_ws;                    // 8 MiB
    const size_t WP_BYTES = (size_t)N_DIM * K_DIM * 2;             // 8388608
    const size_t AP_BYTES = (size_t)M_TOTAL * K_DIM * 2;           // 268435456

    repack_w<<<dim3(1024), dim3(256), 0, stream>>>(W, Wp);

    if (ws_size >= WP_BYTES + AP_BYTES) {
        unsigned short* Ap = (unsigned short*)((char*)d_ws + WP_BYTES);
        gather_convert<<<dim3(32768), dim3(256), 0, stream>>>(X, Ap);
        gemm_8p<<<dim3(512), dim3(512), 0, stream>>>(Ap, Wp, out);
    } else {
        merge_gemm<<<dim3((M_TOTAL / BM) * (N_DIM / BN)), dim3(256), 0, stream>>>(X, Wp, out);
    }
}

// Round 3
// 956.198 us; speedup vs baseline: 1.0991x; 1.0091x over previous
//
#include <hip/hip_runtime.h>
#include <hip/hip_bf16.h>
#include <stdint.h>

// LinearPatchMerger: (1,131072,1024) fp32 patches, merge 2x2 -> (32768,4096),
// out = merged @ W.T, W (1024,4096) fp32. Output (1,32768,1024) fp32.
//
// Round-5 = round-4 resubmit (round-4 bench died to container/push infra,
// not kernel: no pass/fail, no compile error; schedule re-audited, all
// RAW/WAR chains + barrier counts verified).
//   pass 1: repack W -> bf16, K-permuted (k' = s*1024 + d)          [8 MiB]
//   pass 2: gather+convert X -> merged bf16 A' (32768 x 4096)       [256 MiB]
//   pass 3: 256x256x64 8-phase bf16 GEMM with ds_reads HOISTED one
//           phase ahead (LDS unit overlaps matrix pipe; round-3 was at
//           the serial LDS+MFMA bound: 4608+4966 cyc/iter/CU = 249 us
//           measured). MMA quadrant order (0,0),(1,0),(0,1),(1,1);
//           vmcnt(2) gates at ph1/ph5; read bursts {8,4,4,8}x2.
// Fallback (small ws): round-1 fused gather-GEMM (passed, ~600 us).

#define M_TOTAL 32768
#define K_DIM   4096
#define N_DIM   1024
#define BM 128
#define BN 128
#define BK 64

typedef __attribute__((ext_vector_type(8))) short short8;
typedef __attribute__((ext_vector_type(4))) float f32x4;
typedef __attribute__((ext_vector_type(8))) unsigned short us8;

#define ASYNC_COPY16(gsrc, ldst)                                                     \
    __builtin_amdgcn_global_load_lds(                                                \
        (const __attribute__((address_space(1))) unsigned int*)(const void*)(gsrc),  \
        (__attribute__((address_space(3))) unsigned int*)(ldst), 16, 0, 0)

static __device__ __forceinline__ unsigned pack2bf(float lo, float hi) {
    unsigned a = __builtin_bit_cast(unsigned, lo) + 0x8000u;
    unsigned b = __builtin_bit_cast(unsigned, hi) + 0x8000u;
    return __builtin_amdgcn_perm(b, a, 0x07060302);
}

// ---------------- pass 1: Wp[j, s*1024+d] = bf16(W[j, d*4+s]) ----------------
__global__ __launch_bounds__(256) void repack_w(const float* __restrict__ W,
                                                unsigned short* __restrict__ Wp) {
    int t = blockIdx.x * 256 + threadIdx.x;
    int j  = t >> 8;
    int d0 = (t & 255) << 2;
    const float4* src = (const float4*)(W + (size_t)j * K_DIM + (size_t)d0 * 4);
    float4 v0 = src[0], v1 = src[1], v2 = src[2], v3 = src[3];
    float vs[4][4] = {{v0.x, v1.x, v2.x, v3.x},
                      {v0.y, v1.y, v2.y, v3.y},
                      {v0.z, v1.z, v2.z, v3.z},
                      {v0.w, v1.w, v2.w, v3.w}};
#pragma unroll
    for (int s = 0; s < 4; s++) {
        uint2 o;
        o.x = pack2bf(vs[s][0], vs[s][1]);
        o.y = pack2bf(vs[s][2], vs[s][3]);
        *(uint2*)(Wp + (size_t)j * K_DIM + s * 1024 + d0) = o;
    }
}

// -------- pass 2: A'[m, s*1024+d] = bf16(X[p, d]); 16 floats/thread ---------
__global__ __launch_bounds__(256) void gather_convert(const float* __restrict__ X,
                                                      unsigned short* __restrict__ Ap) {
    int idx = blockIdx.x * 256 + threadIdx.x;   // 8.39M threads
    int p   = idx >> 6;                          // 64 threads per patch row
    int c16 = (idx & 63) << 4;                   // float col, 16 per thread
    int img = p >> 14;
    int r   = p & 16383;
    int pi  = r >> 7;
    int pj  = r & 127;
    int m   = img * 4096 + (pi >> 1) * 64 + (pj >> 1);
    int s   = ((pi & 1) << 1) | (pj & 1);
    const float4* src = (const float4*)(X + (size_t)p * 1024 + c16);
    float4 v0 = src[0], v1 = src[1], v2 = src[2], v3 = src[3];
    uint4 o0, o1;
    o0.x = pack2bf(v0.x, v0.y); o0.y = pack2bf(v0.z, v0.w);
    o0.z = pack2bf(v1.x, v1.y); o0.w = pack2bf(v1.z, v1.w);
    o1.x = pack2bf(v2.x, v2.y); o1.y = pack2bf(v2.z, v2.w);
    o1.z = pack2bf(v3.x, v3.y); o1.w = pack2bf(v3.z, v3.w);
    uint4* dst = (uint4*)(Ap + (size_t)m * K_DIM + s * 1024 + c16);
    dst[0] = o0;
    dst[1] = o1;
}

// ---------------- pass 3: 256x256x64 8-phase bf16 GEMM, hoisted reads -------
// LDS: lds[slot][op][half] of 16 KiB halves; st_16x32 XOR swizzle via
// pre-swizzled global_load_lds source.
// Stage phases: ph0:A1h1(ko) ph1:B0h0(ne) ph2:A0h0(ne) ph3:B0h1(ne)
//   ph4:A0h1(ne) ph5:B1h0(no) ph6:A1h0(no) ph7:B1h1(no)
// Gates: vmcnt(2) end of ph1 (slot1-odd fully landed) and ph5 (slot0-ne).
// Hoisted ds_reads (issued at p, consumed at p+1..p+3):
//   ph0:aQ=A0h1  ph1:b1=B0h1  ph2:b0=B1h0  ph3:aP=A1h0
//   ph4:aQ=A1h1  ph5:b1=B1h1  ph6:b0=B0h0' ph7:aP=A0h0'
// MMA order: ph0 (0,0)e  ph1 (1,0)e  ph2 (0,1)e  ph3 (1,1)e, same for odd.
// Verified per-half: stage-issue < drain-gate < hoisted-read < next-writer,
// and every phase's concurrent stage target is disjoint from its read target.
#define NT 32   // 64 K-tiles / 2 per iteration

#define SBAR() do { asm volatile("" ::: "memory");            \
                    __builtin_amdgcn_s_barrier();             \
                    asm volatile("" ::: "memory"); } while (0)
#define WAITLG()  asm volatile("s_waitcnt lgkmcnt(0)" ::: "memory")
#define WAITVM2() asm volatile("s_waitcnt vmcnt(2)" ::: "memory")
#define WAITVM6() asm volatile("s_waitcnt vmcnt(6)" ::: "memory")
#define SCHED0()  __builtin_amdgcn_sched_barrier(0)
#define PRIO1()   __builtin_amdgcn_s_setprio(1)
#define PRIO0()   __builtin_amdgcn_s_setprio(0)

__global__ __launch_bounds__(512, 2) void gemm_8p(
        const unsigned short* __restrict__ Ap,  // (32768,4096) bf16, permuted K
        const unsigned short* __restrict__ Wp,  // (1024,4096) bf16, permuted K
        float* __restrict__ out) {              // (32768,1024) fp32
    __shared__ unsigned short lds[2][2][2][8192];  // 128 KiB

    const int tid  = threadIdx.x;
    const int lane = tid & 63;
    const int wave = tid >> 6;      // 8 waves: wr = wave>>2 (M), wc = wave&3 (N)
    const int wr   = wave >> 2;
    const int wc   = wave & 3;
    const int lrow = lane & 15;
    const int quad = lane >> 4;

    // XCD-chunked bijective swizzle: 512 blocks, 64 per XCD; n-minor so the
    // 4 blocks sharing an A panel are adjacent within one XCD's chunk.
    const int bid = blockIdx.x;
    const int lw  = (bid & 7) * 64 + (bid >> 3);
    const int bn  = (lw & 3) * 256;
    const int bm  = (lw >> 2) * 256;

    // Staging source addressing (pre-swizzled global source; LDS linear).
    const int rho   = lane >> 2;
    const int kappa = (lane & 3) ^ ((lane >> 5) << 1);
    const int r128s = wave * 16 + rho;          // wave stages slab==wave
    const unsigned short* aptr[2];
    const unsigned short* bptr[2];
#pragma unroll
    for (int h = 0; h < 2; h++) {
        const int ra = ((r128s >> 6) << 7) + h * 64 + (r128s & 63);
        const int rb = ((r128s >> 5) << 6) + h * 32 + (r128s & 31);
        aptr[h] = Ap + (size_t)(bm + ra) * K_DIM + kappa * 8;
        bptr[h] = Wp + (size_t)(bn + rb) * K_DIM + kappa * 8;
    }

#define STAGE_A(slot, h, kt) do {                                                 \
    ASYNC_COPY16(aptr[h] + (kt) * 64,      &lds[slot][0][h][wave * 1024]);        \
    ASYNC_COPY16(aptr[h] + (kt) * 64 + 32, &lds[slot][0][h][wave * 1024 + 512]);  \
} while (0)
#define STAGE_B(slot, h, kt) do {                                                 \
    ASYNC_COPY16(bptr[h] + (kt) * 64,      &lds[slot][1][h][wave * 1024]);        \
    ASYNC_COPY16(bptr[h] + (kt) * 64 + 32, &lds[slot][1][h][wave * 1024 + 512]);  \
} while (0)

    // ds_read swizzled row/chunk offset within a subtile (16-B aligned)
    const int rswz = (lrow * 64 + quad * 16) ^ ((lrow & 8) << 2);
    short8 aP[4][2], aQ[4][2], b0[2][2], b1[2][2];
    f32x4 acc[8][4] = {};

#define LDA_R(dst, slot, mh) do {                                                 \
    const char* base_ = (const char*)&lds[slot][0][mh][0] + rswz;                 \
    _Pragma("unroll") for (int ii = 0; ii < 4; ii++)                              \
    _Pragma("unroll") for (int kk = 0; kk < 2; kk++)                              \
        dst[ii][kk] = *(const short8*)(base_ + (wr * 4 + ii) * 2048 + kk * 1024); \
} while (0)
#define LDB_R(dst, slot, nh) do {                                                 \
    const char* base_ = (const char*)&lds[slot][1][nh][0] + rswz;                 \
    _Pragma("unroll") for (int jj = 0; jj < 2; jj++)                              \
    _Pragma("unroll") for (int kk = 0; kk < 2; kk++)                              \
        dst[jj][kk] = *(const short8*)(base_ + (wc * 2 + jj) * 2048 + kk * 1024); \
} while (0)
#define MMA(mh, nh, areg, breg) do {                                              \
    _Pragma("unroll") for (int ii = 0; ii < 4; ii++)                              \
    _Pragma("unroll") for (int jj = 0; jj < 2; jj++)                              \
    _Pragma("unroll") for (int kk = 0; kk < 2; kk++)                              \
        acc[(mh) * 4 + ii][(nh) * 2 + jj] =                                       \
            __builtin_amdgcn_mfma_f32_16x16x32_bf16(                              \
                areg[ii][kk], breg[jj][kk], acc[(mh) * 4 + ii][(nh) * 2 + jj],    \
                0, 0, 0);                                                         \
} while (0)

    // prologue: K-tile 0 (4 halves) -> slot0; K-tile 1 first 3 halves -> slot1
    STAGE_B(0, 0, 0); STAGE_A(0, 0, 0); STAGE_B(0, 1, 0); STAGE_A(0, 1, 0);
    STAGE_B(1, 0, 1); STAGE_A(1, 0, 1); STAGE_B(1, 1, 1);
    WAITVM6();        // all of K-tile 0 landed (3 half-tiles stay in flight)
    SBAR();
    LDA_R(aP, 0, 0); LDB_R(b0, 0, 0);   // hoisted reads for ph0's MMA(0,0)

#pragma unroll 1
    for (int t = 0; t < NT; t++) {
        const int ko = 2 * t + 1;          // this iteration's odd K-tile
        const int ne = (2 * t + 2) & 63;   // next even (wraps harmlessly at end)
        const int no = (2 * t + 3) & 63;   // next odd

        // ph0: stage odd A-h1; read aQ=A0h1(e); MFMA Q(0,0) even
        STAGE_A(1, 1, ko);
        SBAR(); WAITLG(); SCHED0();
        LDA_R(aQ, 0, 1);
        SCHED0();
        PRIO1(); MMA(0, 0, aP, b0); PRIO0();
        SBAR();
        // ph1: stage ne B-h0; read b1=B0h1(e); MFMA Q(1,0) even; gate slot1
        STAGE_B(0, 0, ne);
        SBAR(); WAITLG(); SCHED0();
        LDB_R(b1, 0, 1);
        SCHED0();
        PRIO1(); MMA(1, 0, aQ, b0); PRIO0();
        WAITVM2();
        SBAR();
        // ph2: stage ne A-h0; read b0=B1h0(o); MFMA Q(0,1) even
        STAGE_A(0, 0, ne);
        SBAR(); WAITLG(); SCHED0();
        LDB_R(b0, 1, 0);
        SCHED0();
        PRIO1(); MMA(0, 1, aP, b1); PRIO0();
        SBAR();
        // ph3: stage ne B-h1; read aP=A1h0(o); MFMA Q(1,1) even
        STAGE_B(0, 1, ne);
        SBAR(); WAITLG(); SCHED0();
        LDA_R(aP, 1, 0);
        SCHED0();
        PRIO1(); MMA(1, 1, aQ, b1); PRIO0();
        SBAR();
        // ph4: stage ne A-h1; read aQ=A1h1(o); MFMA Q(0,0) odd
        STAGE_A(0, 1, ne);
        SBAR(); WAITLG(); SCHED0();
        LDA_R(aQ, 1, 1);
        SCHED0();
        PRIO1(); MMA(0, 0, aP, b0); PRIO0();
        SBAR();
        // ph5: stage no B-h0; read b1=B1h1(o); MFMA Q(1,0) odd; gate slot0-ne
        STAGE_B(1, 0, no);
        SBAR(); WAITLG(); SCHED0();
        LDB_R(b1, 1, 1);
        SCHED0();
        PRIO1(); MMA(1, 0, aQ, b0); PRIO0();
        WAITVM2();
        SBAR();
        // ph6: stage no A-h0; read b0=B0h0(ne); MFMA Q(0,1) odd
        STAGE_A(1, 0, no);
        SBAR(); WAITLG(); SCHED0();
        LDB_R(b0, 0, 0);
        SCHED0();
        PRIO1(); MMA(0, 1, aP, b1); PRIO0();
        SBAR();
        // ph7: stage no B-h1; read aP=A0h0(ne); MFMA Q(1,1) odd
        STAGE_B(1, 1, no);
        SBAR(); WAITLG(); SCHED0();
        LDA_R(aP, 0, 0);
        SCHED0();
        PRIO1(); MMA(1, 1, aQ, b1); PRIO0();
        SBAR();
    }

    asm volatile("s_waitcnt vmcnt(0) lgkmcnt(0)" ::: "memory");  // drain

    const int ocol = bn + wc * 64 + lrow;
#pragma unroll
    for (int i = 0; i < 8; i++) {
#pragma unroll
        for (int r = 0; r < 4; r++) {
            float* po = out + (size_t)(bm + wr * 128 + i * 16 + quad * 4 + r) * N_DIM + ocol;
#pragma unroll
            for (int j = 0; j < 4; j++)
                po[j * 16] = acc[i][j][r];
        }
    }
}

// ---------------- fallback: round-1 fused gather-GEMM (passed) --------------
#define LP 72
__global__ __launch_bounds__(256) void merge_gemm(
        const float* __restrict__ X,
        const unsigned short* __restrict__ Wp,
        float* __restrict__ out) {
    __shared__ unsigned short As[BM][LP];
    __shared__ unsigned short Bs[BN][LP];

    const int tid  = threadIdx.x;
    const int lane = tid & 63;
    const int wave = tid >> 6;
    const int wm   = (wave >> 1) * 64;
    const int wn   = (wave & 1) * 64;
    const int lrow = lane & 15;
    const int quad = lane >> 4;

    const int blk = blockIdx.x;
    const int bn  = (blk & 7) * BN;
    const int bm  = (blk >> 3) * BM;

    const int arow = tid >> 4;
    const int acol = (tid & 15) << 2;

    const float* abase[8];
#pragma unroll
    for (int rep = 0; rep < 8; rep++) {
        int m   = bm + arow + rep * 16;
        int img = m >> 12;
        int r   = m & 4095;
        int bi  = r >> 6;
        int bj  = r & 63;
        int pbase = img * 16384 + bi * 256 + bj * 2;
        abase[rep] = X + (size_t)pbase * 1024 + acol;
    }

    const int brow = tid >> 3;
    const int bcol = (tid & 7) << 3;

    f32x4 acc[4][4] = {};

    for (int k0 = 0; k0 < K_DIM; k0 += BK) {
        const int s    = k0 >> 10;
        const int d0   = k0 & 1023;
        const int aoff = (((s >> 1) * 128) + (s & 1)) * 1024 + d0;

#pragma unroll
        for (int rep = 0; rep < 8; rep++) {
            const float4 v = *(const float4*)(abase[rep] + aoff);
            uint2 o;
            o.x = pack2bf(v.x, v.y);
            o.y = pack2bf(v.z, v.w);
            *(uint2*)&As[arow + rep * 16][acol] = o;
        }
#pragma unroll
        for (int rep = 0; rep < 4; rep++) {
            us8 v = *(const us8*)(Wp + (size_t)(bn + brow + rep * 32) * K_DIM + k0 + bcol);
            *(us8*)&Bs[brow + rep * 32][bcol] = v;
        }
        __syncthreads();

#pragma unroll
        for (int kk = 0; kk < 2; kk++) {
            const int koff = kk * 32 + quad * 8;
            short8 a[4], b[4];
#pragma unroll
            for (int i = 0; i < 4; i++)
                a[i] = *(const short8*)&As[wm + i * 16 + lrow][koff];
#pragma unroll
            for (int j = 0; j < 4; j++)
                b[j] = *(const short8*)&Bs[wn + j * 16 + lrow][koff];
#pragma unroll
            for (int i = 0; i < 4; i++)
#pragma unroll
                for (int j = 0; j < 4; j++)
                    acc[i][j] = __builtin_amdgcn_mfma_f32_16x16x32_bf16(
                        a[i], b[j], acc[i][j], 0, 0, 0);
        }
        __syncthreads();
    }

    const int ocol = bn + wn + lrow;
#pragma unroll
    for (int i = 0; i < 4; i++) {
#pragma unroll
        for (int r = 0; r < 4; r++) {
            float* po = out + (size_t)(bm + wm + i * 16 + quad * 4 + r) * N_DIM + ocol;
#pragma unroll
            for (int j = 0; j < 4; j++)
                po[j * 16] = acc[i][j][r];
        }
    }
}

extern "C" void kernel_launch(void* const* d_in, const int* in_sizes, int n_in,
                              void* d_out, int out_size, void* d_ws, size_t ws_size,
                              hipStream_t stream) {
    const float* X = (const float*)d_in[0];
    const float* W = (const float*)d_in[2];
    float* out = (float*)d_out;

    unsigned short* Wp = (unsigned short*)d_ws;                    // 8 MiB
    const size_t WP_BYTES = (size_t)N_DIM * K_DIM * 2;             // 8388608
    const size_t AP_BYTES = (size_t)M_TOTAL * K_DIM * 2;           // 268435456

    repack_w<<<dim3(1024), dim3(256), 0, stream>>>(W, Wp);

    if (ws_size >= WP_BYTES + AP_BYTES) {
        unsigned short* Ap = (unsigned short*)((char*)d_ws + WP_BYTES);
        gather_convert<<<dim3(32768), dim3(256), 0, stream>>>(X, Ap);
        gemm_8p<<<dim3(512), dim3(512), 0, stream>>>(Ap, Wp, out);
    } else {
        merge_gemm<<<dim3((M_TOTAL / BM) * (N_DIM / BN)), dim3(256), 0, stream>>>(X, Wp, out);
    }
}